// Round 10
// baseline (107.957 us; speedup 1.0000x reference)
//
#include <hip/hip_runtime.h>
#include <hip/hip_bf16.h>
#include <cstdint>
#include <cstddef>

#define NUM_CLASS 1000
#define NPAD      1024
#define LOW_DIM   128
#define B_UPD     1024
#define B_SIM     65536

typedef short bf16x8 __attribute__((ext_vector_type(8)));
typedef float f32x4  __attribute__((ext_vector_type(4)));

__device__ __forceinline__ unsigned short f2bf(float f) {
  union { float f; unsigned u; } a; a.f = f;
  unsigned u = a.u;
  return (unsigned short)((u + 0x7fffu + ((u >> 16) & 1u)) >> 16);  // RNE
}

// ---------- kernel 1: per-class EMA (ballot scan) + L2 norm -> fragment-swizzled bf16 ----------
// Updates to different labels commute, so per-class in-order processing
// reproduces the reference lax.scan exactly.
// Output layout = MFMA B-operand fragment order (lane l: col=l&15, k=(l>>4)*8+e):
//   slot[((g*4 + kk)*64 + l) * 8 + e]  (ushort units)
//   holds logical B[row = g*16 + (l&15)][k = kk*32 + (l>>4)*8 + e]
__global__ void proto_update_kernel(const float* __restrict__ pred_feat,
                                    const int*   __restrict__ labels,
                                    const float* __restrict__ protos_in,
                                    unsigned short* __restrict__ protos_sw) {
  int c = blockIdx.x;    // 0..1023
  int d = threadIdx.x;   // 0..127
  float p = 0.0f;
  if (c < NUM_CLASS) {
    p = protos_in[c * LOW_DIM + d];
    #pragma unroll 4
    for (int k = 0; k < B_UPD / 64; ++k) {
      int lab = labels[k * 64 + (d & 63)];
      unsigned long long m = __ballot(lab == c);   // wave-uniform
      while (m) {
        int b = __builtin_ctzll(m);
        m &= (m - 1);
        p = 0.99f * p + 0.01f * pred_feat[(size_t)(k * 64 + b) * LOW_DIM + d];
      }
    }
  }
  float sq = p * p;
  #pragma unroll
  for (int o = 1; o < 64; o <<= 1) sq += __shfl_xor(sq, o, 64);
  __shared__ float wsum[2];
  if ((d & 63) == 0) wsum[d >> 6] = sq;
  __syncthreads();
  float total = wsum[0] + wsum[1];
  unsigned short v = f2bf(p / fmaxf(sqrtf(total), 1e-12f));  // c>=1000 -> 0
  int g = c >> 4, r = c & 15, kk = d >> 5, j = (d >> 3) & 3, e = d & 7;
  protos_sw[(size_t)((g * 4 + kk) * 64 + j * 16 + r) * 8 + e] = v;
}

// ---------- kernel 2: C[65536,1000] = A(f32->bf16) @ B^T, BARRIER-FREE ----------
// R6 geometry (BM=32, TPB=512, 8 waves, acc[2][8], mfma(feat,proto), proven
// 512B-chunk LDS-transpose epilogue) with ALL block synchronization removed:
// A fragments are loaded straight from global per wave (lane l reads 8
// consecutive f32 of row m0+m*16+(l&15): two dwordx4; the block's 16 KB
// A-panel is L1-resident after first touch) and converted f32->bf16
// in-register. No A staging -> no stage barrier; no smem union -> no
// epilogue barrier. ZERO __syncthreads: the CU's 16 resident waves
// free-run, so stage/compute/store phases of different waves interleave
// and the store stream stays busy continuously instead of phase-aligned
// bursts (R6's ~serial phase model: 18k cyc/block vs 11.5k write-bound).
#define BM   32
#define TPB2 512
#define CPAD 132                 // epilogue f32 LDS row stride (128+4)
#define EPW  (16 * CPAD)         // floats per wave epilogue region (8448 B)

__global__ __launch_bounds__(TPB2, 4)
void gemm_sim_kernel(const float* __restrict__ A,
                     const unsigned short* __restrict__ Bsw,
                     float* __restrict__ C) {
  __shared__ float Tbuf[8 * EPW];              // 67584 B -> 2 blocks/CU
  int t  = threadIdx.x;
  int m0 = blockIdx.x * BM;

  int lane = t & 63;
  int w    = t >> 6;
  int lr   = lane & 15;
  int hi   = lane >> 4;                        // 0..3

  f32x4 acc[2][8];
  #pragma unroll
  for (int m = 0; m < 2; ++m)
    #pragma unroll
    for (int n = 0; n < 8; ++n)
      acc[m][n] = (f32x4){0.f, 0.f, 0.f, 0.f};

  #pragma unroll
  for (int kk = 0; kk < 4; ++kk) {             // K = 4 x 32
    bf16x8 af[2];
    #pragma unroll
    for (int m = 0; m < 2; ++m) {
      // a-operand fragment: row = m0 + m*16 + lr, k = kk*32 + hi*8 + e
      const float4* p = reinterpret_cast<const float4*>(
          A + (size_t)(m0 + m * 16 + lr) * LOW_DIM + kk * 32 + hi * 8);
      float4 v0 = p[0], v1 = p[1];
      af[m][0] = (short)f2bf(v0.x); af[m][1] = (short)f2bf(v0.y);
      af[m][2] = (short)f2bf(v0.z); af[m][3] = (short)f2bf(v0.w);
      af[m][4] = (short)f2bf(v1.x); af[m][5] = (short)f2bf(v1.y);
      af[m][6] = (short)f2bf(v1.z); af[m][7] = (short)f2bf(v1.w);
    }
    #pragma unroll
    for (int n = 0; n < 8; ++n) {
      int g = w * 8 + n;                       // 16-class group
      bf16x8 bf = *reinterpret_cast<const bf16x8*>(
          Bsw + ((size_t)(g * 4 + kk) * 64 + lane) * 8);   // coalesced 1KB/wave
      #pragma unroll
      for (int m = 0; m < 2; ++m)
        acc[m][n] = __builtin_amdgcn_mfma_f32_16x16x32_bf16(af[m], bf, acc[m][n], 0, 0, 0);
    }
  }

  // ---- per-wave-private LDS transpose epilogue (wave-local, in-order DS) ----
  // D layout: row(feat) = (lane>>4)*4 + r, col(class-in-group) = lane&15.
  float* myT = Tbuf + w * EPW;
  #pragma unroll
  for (int m = 0; m < 2; ++m) {
    int rbase = hi * 4;
    #pragma unroll
    for (int n = 0; n < 8; ++n) {
      #pragma unroll
      for (int r = 0; r < 4; ++r)
        myT[(rbase + r) * CPAD + n * 16 + lr] = acc[m][n][r];
    }
    #pragma unroll
    for (int it = 0; it < 8; ++it) {
      int idx = it * 64 + lane;
      int row = idx >> 5, c4 = idx & 31;
      f32x4 v = *reinterpret_cast<const f32x4*>(myT + row * CPAD + c4 * 4);
      int col = w * 128 + c4 * 4;
      if (col < NUM_CLASS) {   // only wave 7 tail masked; 1000 % 4 == 0
        *reinterpret_cast<f32x4*>(C + (size_t)(m0 + m * 16 + row) * NUM_CLASS + col) = v;
      }
    }
  }
}

extern "C" void kernel_launch(void* const* d_in, const int* in_sizes, int n_in,
                              void* d_out, int out_size, void* d_ws, size_t ws_size,
                              hipStream_t stream) {
  const float* pred_feat = (const float*)d_in[0];   // [1024,128]
  const int*   labels    = (const int*)d_in[1];     // [1024]
  const float* protos    = (const float*)d_in[2];   // [1000,128]
  const float* feat      = (const float*)d_in[3];   // [65536,128]
  float* out = (float*)d_out;                       // [65536,1000]

  unsigned short* protos_sw = (unsigned short*)d_ws;  // 256 KB fragment-swizzled

  proto_update_kernel<<<NPAD, 128, 0, stream>>>(pred_feat, labels, protos, protos_sw);
  gemm_sim_kernel<<<B_SIM / BM, TPB2, 0, stream>>>(feat, protos_sw, out);
}